// Round 5
// baseline (111.741 us; speedup 1.0000x reference)
//
#include <hip/hip_runtime.h>
#include <math.h>

#define DIM   768
#define BATCH 4096
#define EPSLN 1e-5f

// ---------------------------------------------------------------------------
// Statevector: 9 wires, 512 amps. amp I = (lane<<3) | r. One wave = one row.
//   wires 0..2 -> bits 0..2 of r (in-register, 8 complex amps/lane)
//   wires 3..8 -> lane bits, all xor-exchanges on the VALU pipe (no LDS!):
//     wire:  3           4     5     6     7           8
//     bit:   4           0     1     3     5           2
//     mask:  16          1     2     8     32          4
//     path:  permlane16  dpp   dpp   dpp   permlane32  dpp ror4/ror12+sel
// ---------------------------------------------------------------------------

__host__ __device__ constexpr int bitof(int W) {
  return W == 3 ? 4 : W == 4 ? 0 : W == 5 ? 1 : W == 6 ? 3 : W == 7 ? 5 : 2;
}

template<int CTRL>
__device__ __forceinline__ float dppf(float v) {
  return __int_as_float(__builtin_amdgcn_update_dpp(
      0, __float_as_int(v), CTRL, 0xF, 0xF, false));
}
template<int OFF>
__device__ __forceinline__ float swzf(float v) {
  return __int_as_float(__builtin_amdgcn_ds_swizzle(__float_as_int(v), OFF));
}
__device__ __forceinline__ float xor32f(float v, int lane) {
#if __has_builtin(__builtin_amdgcn_permlane32_swap)
  typedef int i2_t __attribute__((ext_vector_type(2)));
  i2_t r = __builtin_amdgcn_permlane32_swap(__float_as_int(v), __float_as_int(v),
                                            false, false);
  return __int_as_float((lane >= 32) ? r.x : r.y);
#else
  return __shfl_xor(v, 32, 64);
#endif
}
__device__ __forceinline__ float xor16f(float v, int lane) {
#if __has_builtin(__builtin_amdgcn_permlane16_swap)
  typedef int i2_t __attribute__((ext_vector_type(2)));
  i2_t r = __builtin_amdgcn_permlane16_swap(__float_as_int(v), __float_as_int(v),
                                            false, false);
  return __int_as_float(((lane >> 4) & 1) ? r.x : r.y);
#else
  return swzf<0x401F>(v);
#endif
}
// xor4 within 16-lane rows: ror:4 gives lane i-4 (mod 16), ror:12 gives i+4.
__device__ __forceinline__ float xor4f(float v, int lane) {
  const float a = dppf<0x124>(v);   // row_ror:4  -> src lane (i-4) & 15
  const float b = dppf<0x12C>(v);   // row_ror:12 -> src lane (i+4) & 15
  return ((lane >> 2) & 1) ? a : b;
}

template<int M>
__device__ __forceinline__ float lxor(float v, int lane) {
  if constexpr (M == 1)       return dppf<0xB1>(v);    // quad_perm [1,0,3,2]
  else if constexpr (M == 2)  return dppf<0x4E>(v);    // quad_perm [2,3,0,1]
  else if constexpr (M == 4)  return xor4f(v, lane);   // dpp ror4/ror12 + sel
  else if constexpr (M == 8)  return dppf<0x128>(v);   // row_ror:8 == xor 8
  else if constexpr (M == 16) return xor16f(v, lane);  // permlane16_swap
  else                        return xor32f(v, lane);  // permlane32_swap
}

template<int N>
__device__ __forceinline__ void allred(float (&v)[N], int lane) {
#pragma unroll
  for (int q = 0; q < N; ++q) v[q] += lxor<1>(v[q], lane);
#pragma unroll
  for (int q = 0; q < N; ++q) v[q] += lxor<2>(v[q], lane);
#pragma unroll
  for (int q = 0; q < N; ++q) v[q] += lxor<4>(v[q], lane);
#pragma unroll
  for (int q = 0; q < N; ++q) v[q] += lxor<8>(v[q], lane);
#pragma unroll
  for (int q = 0; q < N; ++q) v[q] += lxor<16>(v[q], lane);
#pragma unroll
  for (int q = 0; q < N; ++q) v[q] += lxor<32>(v[q], lane);
}

// RZ: diag(e^{-i t/2}, e^{+i t/2}) — diagonal, zero shuffles.
template<int W>
__device__ __forceinline__ void gate_rz(float (&re)[8], float (&im)[8],
                                        float c, float s, int lane) {
  if constexpr (W < 3) {
#pragma unroll
    for (int r = 0; r < 8; ++r) {
      const float t = ((r >> W) & 1) ? s : -s;
      const float xx = re[r], yy = im[r];
      re[r] = xx * c - yy * t;
      im[r] = yy * c + xx * t;
    }
  } else {
    const float t = ((lane >> bitof(W)) & 1) ? s : -s;
#pragma unroll
    for (int r = 0; r < 8; ++r) {
      const float xx = re[r], yy = im[r];
      re[r] = xx * c - yy * t;
      im[r] = yy * c + xx * t;
    }
  }
}

// RY: [[c, -s], [s, c]]
template<int W>
__device__ __forceinline__ void gate_ry(float (&re)[8], float (&im)[8],
                                        float c, float s, int lane) {
  if constexpr (W < 3) {
#pragma unroll
    for (int r = 0; r < 8; ++r) {
      if (!((r >> W) & 1)) {
        const int r2 = r | (1 << W);
        const float ar = re[r], ai = im[r], br = re[r2], bi = im[r2];
        re[r]  = c * ar - s * br;
        im[r]  = c * ai - s * bi;
        re[r2] = s * ar + c * br;
        im[r2] = s * ai + c * bi;
      }
    }
  } else {
    constexpr int M = 1 << bitof(W);
    const float t = ((lane >> bitof(W)) & 1) ? s : -s;
#pragma unroll
    for (int r = 0; r < 8; ++r) {
      const float ore = lxor<M>(re[r], lane);
      const float oim = lxor<M>(im[r], lane);
      re[r] = c * re[r] + t * ore;
      im[r] = c * im[r] + t * oim;
    }
  }
}

// CNOT(C, T)
template<int C, int T>
__device__ __forceinline__ void gate_cnot(float (&re)[8], float (&im)[8], int lane) {
  if constexpr (C < 3 && T < 3) {          // both local: register permute
#pragma unroll
    for (int r = 0; r < 8; ++r) {
      if (((r >> C) & 1) && !((r >> T) & 1)) {
        const int r2 = r | (1 << T);
        const float tr = re[r], ti = im[r];
        re[r] = re[r2]; im[r] = im[r2];
        re[r2] = tr;    im[r2] = ti;
      }
    }
  } else if constexpr (C < 3) {            // local control, lane target
    constexpr int M = 1 << bitof(T);
#pragma unroll
    for (int r = 0; r < 8; ++r) {
      if ((r >> C) & 1) {
        re[r] = lxor<M>(re[r], lane);
        im[r] = lxor<M>(im[r], lane);
      }
    }
  } else if constexpr (T < 3) {            // lane control, local target: selects
    const bool cc = (lane >> bitof(C)) & 1;
#pragma unroll
    for (int r = 0; r < 8; ++r) {
      if (!((r >> T) & 1)) {
        const int r2 = r | (1 << T);
        const float ar = re[r], ai = im[r], br = re[r2], bi = im[r2];
        re[r]  = cc ? br : ar;  im[r]  = cc ? bi : ai;
        re[r2] = cc ? ar : br;  im[r2] = cc ? ai : bi;
      }
    }
  } else {                                 // lane control, lane target
    constexpr int M = 1 << bitof(T);
    const bool cc = (lane >> bitof(C)) & 1;
#pragma unroll
    for (int r = 0; r < 8; ++r) {
      const float orr = lxor<M>(re[r], lane);
      const float oii = lxor<M>(im[r], lane);
      re[r] = cc ? orr : re[r];
      im[r] = cc ? oii : im[r];
    }
  }
}

__device__ __forceinline__ void cmul(float& dr, float& di,
                                     float ar, float ai, float br, float bi) {
  const float rr = ar * br - ai * bi;
  const float ii = ar * bi + ai * br;
  dr = rr; di = ii;
}

// ---------------------------------------------------------------------------
__global__ void precompute_trig(const float* __restrict__ qw, float* __restrict__ cs) {
  const int i = threadIdx.x;
  if (i < 36) {
    float s, c;
    sincosf(0.5f * qw[i], &s, &c);
    cs[2 * i]     = c;
    cs[2 * i + 1] = s;
  }
}

// ---------------------------------------------------------------------------
// One wave per row. enc+L0 as closed-form product state; all shuffles VALU.
// ---------------------------------------------------------------------------
__global__ __launch_bounds__(256, 4)
void quantum_fused(const float* __restrict__ x,
                   const float* __restrict__ w_in,
                   const float* __restrict__ b_in,
                   const float* __restrict__ gamma,
                   const float* __restrict__ beta,
                   const float* __restrict__ w_out,
                   const float* __restrict__ b_out,
                   const float* __restrict__ cs,
                   float* __restrict__ out) {
  const int lane = threadIdx.x & 63;
  const int wv   = threadIdx.x >> 6;
  const int row  = blockIdx.x * 4 + wv;

  const float4* xv = (const float4*)(x + (size_t)row * DIM);
  float4 xr[3];
#pragma unroll
  for (int k = 0; k < 3; ++k) xr[k] = xv[lane + 64 * k];

  // ---- input projection ----
  float h[8];
#pragma unroll
  for (int q = 0; q < 8; ++q) {
    const float4* wq = (const float4*)(w_in + q * DIM);
    float acc = 0.f;
#pragma unroll
    for (int k = 0; k < 3; ++k) {
      const float4 w4 = wq[lane + 64 * k];
      acc += xr[k].x * w4.x + xr[k].y * w4.y + xr[k].z * w4.z + xr[k].w * w4.w;
    }
    h[q] = acc;
  }
  allred(h, lane);

  // ---- bias + tanh + LayerNorm ----
#pragma unroll
  for (int q = 0; q < 8; ++q) h[q] = tanhf(h[q] + b_in[q]);
  float mu = 0.f;
#pragma unroll
  for (int q = 0; q < 8; ++q) mu += h[q];
  mu *= 0.125f;
  float var = 0.f;
#pragma unroll
  for (int q = 0; q < 8; ++q) { const float d = h[q] - mu; var += d * d; }
  var *= 0.125f;
  const float inv = 1.0f / sqrtf(var + EPSLN);
  float ang[8];
#pragma unroll
  for (int q = 0; q < 8; ++q)
    ang[q] = (h[q] - mu) * inv * gamma[q] + beta[q];

  // ---- product state after enc + layer-0 (all single-qubit) ----
  // psi_i = RZ(w1i)·RX(w0i)·RZ(a)·RX(a)|0>, wire 8 stays |0>.
  float f0r[8], f0i[8], f1r[8], f1i[8];
#pragma unroll
  for (int i = 0; i < 8; ++i) {
    float sa, ca;
    __sincosf(0.5f * ang[i], &sa, &ca);
    const float p0r = ca * ca, p0i = -ca * sa;     // e^{-ia/2} cos(a/2)
    const float p1r = sa * sa, p1i = -sa * ca;     // -i e^{+ia/2} sin(a/2)
    const float c0 = cs[2 * i],        s0 = cs[2 * i + 1];        // RX(w[0,i])
    const float cz = cs[2 * (9 + i)],  sz = cs[2 * (9 + i) + 1];  // RZ(w[1,i])
    const float q0r = c0 * p0r + s0 * p1i, q0i = c0 * p0i - s0 * p1r;
    const float q1r = s0 * p0i + c0 * p1r, q1i = -s0 * p0r + c0 * p1i;
    f0r[i] = cz * q0r + sz * q0i;  f0i[i] = cz * q0i - sz * q0r;
    f1r[i] = cz * q1r - sz * q1i;  f1i[i] = cz * q1i + sz * q1r;
  }

  // local tensor over wires 0..2 -> t[8]
  float tr[8], ti[8];
  tr[0] = f0r[0]; ti[0] = f0i[0];
  tr[1] = f1r[0]; ti[1] = f1i[0];
#pragma unroll
  for (int b = 0; b < 2; ++b) {
    cmul(tr[2 + b], ti[2 + b], tr[b], ti[b], f1r[1], f1i[1]);
    cmul(tr[b],     ti[b],     tr[b], ti[b], f0r[1], f0i[1]);
  }
#pragma unroll
  for (int b = 0; b < 4; ++b) {
    cmul(tr[4 + b], ti[4 + b], tr[b], ti[b], f1r[2], f1i[2]);
    cmul(tr[b],     ti[b],     tr[b], ti[b], f0r[2], f0i[2]);
  }

  // lane factor over wires 3..7 (wire 8 bit -> amplitude is zero)
  float Lr, Li;
  {
    const bool b3 = (lane >> bitof(3)) & 1;
    Lr = b3 ? f1r[3] : f0r[3];
    Li = b3 ? f1i[3] : f0i[3];
#pragma unroll
    for (int i = 4; i < 8; ++i) {
      const bool b = (lane >> bitof(i)) & 1;
      const float gr = b ? f1r[i] : f0r[i];
      const float gi = b ? f1i[i] : f0i[i];
      cmul(Lr, Li, Lr, Li, gr, gi);
    }
    if ((lane >> bitof(8)) & 1) { Lr = 0.f; Li = 0.f; }
  }

  float re[8], im[8];
#pragma unroll
  for (int r = 0; r < 8; ++r) {
    re[r] = tr[r] * Lr - ti[r] * Li;
    im[r] = tr[r] * Li + ti[r] * Lr;
  }

  // ---- layers 1..3 ----
#define LSTEP(l, i, j) { gate_cnot<i, j>(re, im, lane);                        \
                         const float c_ = cs[2*((l)*9+(i))];                   \
                         const float s_ = cs[2*((l)*9+(i))+1];                 \
                         gate_ry<i>(re, im, c_, s_, lane);                     \
                         gate_rz<i>(re, im, c_, s_, lane); }
#define LAYER(l)                                                               \
  LSTEP(l,0,1) LSTEP(l,1,2) LSTEP(l,2,3) LSTEP(l,3,4)                          \
  LSTEP(l,4,5) LSTEP(l,5,6) LSTEP(l,6,7) LSTEP(l,7,0)                          \
  { gate_cnot<7, 8>(re, im, lane);                                             \
    gate_ry<8>(re, im, cs[2*((l)*9+8)], cs[2*((l)*9+8)+1], lane); }
  LAYER(1) LAYER(2) LAYER(3)
#undef LAYER
#undef LSTEP

  // ---- measurement ----
  float p[8];
#pragma unroll
  for (int r = 0; r < 8; ++r) p[r] = re[r] * re[r] + im[r] * im[r];
  float ptot = 0.f;
#pragma unroll
  for (int r = 0; r < 8; ++r) ptot += p[r];
  float z[8];
#pragma unroll
  for (int i = 0; i < 3; ++i) {
    float acc = 0.f;
#pragma unroll
    for (int r = 0; r < 8; ++r) acc += ((r >> i) & 1) ? -p[r] : p[r];
    z[i] = acc;
  }
#pragma unroll
  for (int i = 3; i < 8; ++i)
    z[i] = ((lane >> bitof(i)) & 1) ? -ptot : ptot;
  allred(z, lane);

  // ---- output projection + residual ----
  float* orow = out + (size_t)row * DIM;
  float4* ov = (float4*)orow;
  const float4* bv = (const float4*)b_out;
#pragma unroll
  for (int k = 0; k < 3; ++k) {
    const int j4 = lane + 64 * k;
    const float4 b4 = bv[j4];
    const float4* wo = (const float4*)(w_out + (size_t)j4 * 32);
    const float4 r0a = wo[0], r0b = wo[1];
    const float4 r1a = wo[2], r1b = wo[3];
    const float4 r2a = wo[4], r2b = wo[5];
    const float4 r3a = wo[6], r3b = wo[7];
    float4 o;
    o.x = xr[k].x + b4.x + z[0]*r0a.x + z[1]*r0a.y + z[2]*r0a.z + z[3]*r0a.w
                        + z[4]*r0b.x + z[5]*r0b.y + z[6]*r0b.z + z[7]*r0b.w;
    o.y = xr[k].y + b4.y + z[0]*r1a.x + z[1]*r1a.y + z[2]*r1a.z + z[3]*r1a.w
                        + z[4]*r1b.x + z[5]*r1b.y + z[6]*r1b.z + z[7]*r1b.w;
    o.z = xr[k].z + b4.z + z[0]*r2a.x + z[1]*r2a.y + z[2]*r2a.z + z[3]*r2a.w
                        + z[4]*r2b.x + z[5]*r2b.y + z[6]*r2b.z + z[7]*r2b.w;
    o.w = xr[k].w + b4.w + z[0]*r3a.x + z[1]*r3a.y + z[2]*r3a.z + z[3]*r3a.w
                        + z[4]*r3b.x + z[5]*r3b.y + z[6]*r3b.z + z[7]*r3b.w;
    ov[j4] = o;
  }
}

extern "C" void kernel_launch(void* const* d_in, const int* in_sizes, int n_in,
                              void* d_out, int out_size, void* d_ws, size_t ws_size,
                              hipStream_t stream) {
  const float* x     = (const float*)d_in[0];
  const float* w_in  = (const float*)d_in[1];
  const float* b_in  = (const float*)d_in[2];
  const float* gamma = (const float*)d_in[3];
  const float* beta  = (const float*)d_in[4];
  const float* q_w   = (const float*)d_in[5];
  const float* w_out = (const float*)d_in[6];
  const float* b_out = (const float*)d_in[7];
  float* outp = (float*)d_out;
  float* cs   = (float*)d_ws;   // 72 floats: (cos, sin) of q_w/2

  hipLaunchKernelGGL(precompute_trig, dim3(1), dim3(64), 0, stream, q_w, cs);
  hipLaunchKernelGGL(quantum_fused, dim3(BATCH / 4), dim3(256), 0, stream,
                     x, w_in, b_in, gamma, beta, w_out, b_out, cs, outp);
}

// Round 10
// 102.081 us; speedup vs baseline: 1.0946x; 1.0946x over previous
//
#include <hip/hip_runtime.h>
#include <math.h>

#define DIM   768
#define BATCH 4096
#define EPSLN 1e-5f

// ---------------------------------------------------------------------------
// Statevector: 9 wires, 512 amps. amp I = (lane<<3) | r. One wave = one row.
//   LOCAL wires {0,1,8} -> r-bits {0,1,2} (8 complex amps/lane, v2f-packed)
//   LANE  wires 2..7 -> lane bits:
//     wire:  2     3     4     5     6     7
//     bit:   2     0     1     3     4     5
//     mask:  4     1     2     8     16    32
//     path:  dsswz dpp   dpp   dpp   dsswz ds_bpermute
//   Shuffle load split across DS pipe (masks 4,16,32) and VALU DPP (1,2,8).
//   Gate math packed as v2f (re,im) -> v_pk_fma_f32 class ops.
// ---------------------------------------------------------------------------

typedef float v2f __attribute__((ext_vector_type(2)));

__device__ __forceinline__ v2f pkfma(v2f a, v2f b, v2f c) {
  return __builtin_elementwise_fma(a, b, c);
}

template<int CTRL>
__device__ __forceinline__ float dppf(float v) {
  return __int_as_float(__builtin_amdgcn_update_dpp(
      0, __float_as_int(v), CTRL, 0xF, 0xF, false));
}
template<int OFF>
__device__ __forceinline__ float swzf(float v) {
  return __int_as_float(__builtin_amdgcn_ds_swizzle(__float_as_int(v), OFF));
}

template<int M>
__device__ __forceinline__ float lxor(float v, int bpx) {
  if constexpr (M == 1)       return dppf<0xB1>(v);    // quad_perm [1,0,3,2]
  else if constexpr (M == 2)  return dppf<0x4E>(v);    // quad_perm [2,3,0,1]
  else if constexpr (M == 4)  return swzf<0x101F>(v);  // ds_swizzle xor 4
  else if constexpr (M == 8)  return dppf<0x128>(v);   // row_ror:8 == xor 8
  else if constexpr (M == 16) return swzf<0x401F>(v);  // ds_swizzle xor 16
  else return __int_as_float(__builtin_amdgcn_ds_bpermute(bpx, __float_as_int(v)));
}
template<int M>
__device__ __forceinline__ v2f lxor2(v2f v, int bpx) {
  v2f r; r.x = lxor<M>(v.x, bpx); r.y = lxor<M>(v.y, bpx); return r;
}

__host__ __device__ constexpr int wbit(int w) {   // lane wires 2..7
  return w == 2 ? 2 : w == 3 ? 0 : w == 4 ? 1 : w == 5 ? 3 : w == 6 ? 4 : 5;
}
__host__ __device__ constexpr int wmask(int w) { return 1 << wbit(w); }

__device__ __forceinline__ float rdlane(float v, int l) {
  return __int_as_float(__builtin_amdgcn_readlane(__float_as_int(v), l));
}
__device__ __forceinline__ float rdfirst(float v) {
  return __int_as_float(__builtin_amdgcn_readfirstlane(__float_as_int(v)));
}

__device__ __forceinline__ v2f cmul(v2f a, v2f b) {
  v2f r;
  r.x = fmaf(a.x, b.x, -(a.y * b.y));
  r.y = fmaf(a.x, b.y,   a.y * b.x);
  return r;
}

// ---- gates -----------------------------------------------------------------
// RZ on local r-bit B: t = bit ? +s : -s; (re,im) = c*(re,im) + t*(-im, re)
template<int B>
__device__ __forceinline__ void rz_local(v2f (&a)[8], float c, float s) {
  const v2f cc = {c, c};
  const v2f t1 = {-s, s};    // r-bit = 1
  const v2f t0 = {s, -s};    // r-bit = 0
#pragma unroll
  for (int r = 0; r < 8; ++r) {
    const v2f tt = ((r >> B) & 1) ? t1 : t0;
    v2f sw; sw.x = a[r].y; sw.y = a[r].x;
    a[r] = pkfma(tt, sw, cc * a[r]);
  }
}
template<int W>
__device__ __forceinline__ void rz_lane(v2f (&a)[8], float c, float s, bool bit) {
  const float t = bit ? s : -s;
  const v2f cc = {c, c}, tv = {-t, t};
#pragma unroll
  for (int r = 0; r < 8; ++r) {
    v2f sw; sw.x = a[r].y; sw.y = a[r].x;
    a[r] = pkfma(tv, sw, cc * a[r]);
  }
}
// RY on local r-bit B
template<int B>
__device__ __forceinline__ void ry_local(v2f (&a)[8], float c, float s) {
  const v2f cc = {c, c}, sv = {s, s}, ns = {-s, -s};
#pragma unroll
  for (int r = 0; r < 8; ++r) {
    if (!((r >> B) & 1)) {
      const int r2 = r | (1 << B);
      const v2f lo = a[r], hi = a[r2];
      a[r]  = pkfma(ns, hi, cc * lo);   // c*lo - s*hi
      a[r2] = pkfma(sv, lo, cc * hi);   // s*lo + c*hi
    }
  }
}
template<int W>
__device__ __forceinline__ void ry_lane(v2f (&a)[8], float c, float s, bool bit, int bpx) {
  constexpr int M = wmask(W);
  const float t = bit ? s : -s;
  const v2f cc = {c, c}, tv = {t, t};
#pragma unroll
  for (int r = 0; r < 8; ++r) {
    const v2f o = lxor2<M>(a[r], bpx);
    a[r] = pkfma(tv, o, cc * a[r]);
  }
}
// CNOT(0,1): local-local, register renames only
__device__ __forceinline__ void cnot01(v2f (&a)[8]) {
  v2f t = a[1]; a[1] = a[3]; a[3] = t;
  t = a[5]; a[5] = a[7]; a[7] = t;
}
// CNOT(1,2): local ctrl bit1, lane target wire2 (mask 4)
__device__ __forceinline__ void cnot12(v2f (&a)[8], int bpx) {
  a[2] = lxor2<4>(a[2], bpx);
  a[3] = lxor2<4>(a[3], bpx);
  a[6] = lxor2<4>(a[6], bpx);
  a[7] = lxor2<4>(a[7], bpx);
}
// CNOT lane-ctrl -> lane-target T
template<int T>
__device__ __forceinline__ void cnot_ll(v2f (&a)[8], bool cc, int bpx) {
  constexpr int M = wmask(T);
#pragma unroll
  for (int r = 0; r < 8; ++r) {
    const v2f o = lxor2<M>(a[r], bpx);
    a[r].x = cc ? o.x : a[r].x;
    a[r].y = cc ? o.y : a[r].y;
  }
}
// CNOT lane-ctrl -> local target r-bit B (selects only)
template<int B>
__device__ __forceinline__ void cnot_lt(v2f (&a)[8], bool cc) {
#pragma unroll
  for (int r = 0; r < 8; ++r) {
    if (!((r >> B) & 1)) {
      const int r2 = r | (1 << B);
      const v2f lo = a[r], hi = a[r2];
      a[r].x  = cc ? hi.x : lo.x;  a[r].y  = cc ? hi.y : lo.y;
      a[r2].x = cc ? lo.x : hi.x;  a[r2].y = cc ? lo.y : hi.y;
    }
  }
}

template<int N>
__device__ __forceinline__ void allred(float (&v)[N], int bpx) {
#pragma unroll
  for (int q = 0; q < N; ++q) v[q] += lxor<1>(v[q], bpx);
#pragma unroll
  for (int q = 0; q < N; ++q) v[q] += lxor<2>(v[q], bpx);
#pragma unroll
  for (int q = 0; q < N; ++q) v[q] += lxor<4>(v[q], bpx);
#pragma unroll
  for (int q = 0; q < N; ++q) v[q] += lxor<8>(v[q], bpx);
#pragma unroll
  for (int q = 0; q < N; ++q) v[q] += lxor<16>(v[q], bpx);
#pragma unroll
  for (int q = 0; q < N; ++q) v[q] += lxor<32>(v[q], bpx);
}

// ---------------------------------------------------------------------------
__global__ void precompute_trig(const float* __restrict__ qw, float* __restrict__ cs) {
  const int i = threadIdx.x;
  if (i < 36) {
    float s, c;
    sincosf(0.5f * qw[i], &s, &c);
    cs[2 * i]     = c;
    cs[2 * i + 1] = s;
  }
}

// ---------------------------------------------------------------------------
__global__ __launch_bounds__(256, 4)
void quantum_fused(const float* __restrict__ x,
                   const float* __restrict__ w_in,
                   const float* __restrict__ b_in,
                   const float* __restrict__ gamma,
                   const float* __restrict__ beta,
                   const float* __restrict__ w_out,
                   const float* __restrict__ b_out,
                   const float* __restrict__ cs,
                   float* __restrict__ out) {
  const int lane = threadIdx.x & 63;
  const int wv   = threadIdx.x >> 6;
  const int row  = blockIdx.x * 4 + wv;
  const int bpx  = ((lane ^ 32) << 2);          // ds_bpermute addr for xor32

  const bool bw2 = (lane >> 2) & 1;  // wire2
  const bool bw3 = (lane >> 0) & 1;  // wire3
  const bool bw4 = (lane >> 1) & 1;  // wire4
  const bool bw5 = (lane >> 3) & 1;  // wire5
  const bool bw6 = (lane >> 4) & 1;  // wire6
  const bool bw7 = (lane >> 5) & 1;  // wire7

  const float4* xv = (const float4*)(x + (size_t)row * DIM);
  float4 xr[3];
#pragma unroll
  for (int k = 0; k < 3; ++k) xr[k] = xv[lane + 64 * k];

  // ---- input projection (packed FMA) ----
  float h[8];
#pragma unroll
  for (int q = 0; q < 8; ++q) {
    const float4* wq = (const float4*)(w_in + q * DIM);
    v2f acc = {0.f, 0.f};
#pragma unroll
    for (int k = 0; k < 3; ++k) {
      const float4 w4 = wq[lane + 64 * k];
      v2f xa; xa.x = xr[k].x; xa.y = xr[k].y;
      v2f xb; xb.x = xr[k].z; xb.y = xr[k].w;
      v2f wa; wa.x = w4.x; wa.y = w4.y;
      v2f wb; wb.x = w4.z; wb.y = w4.w;
      acc = pkfma(xa, wa, acc);
      acc = pkfma(xb, wb, acc);
    }
    h[q] = acc.x + acc.y;
  }
  allred(h, bpx);

  // ---- bias + tanh + LayerNorm ----
#pragma unroll
  for (int q = 0; q < 8; ++q) h[q] = tanhf(h[q] + b_in[q]);
  float mu = 0.f;
#pragma unroll
  for (int q = 0; q < 8; ++q) mu += h[q];
  mu *= 0.125f;
  float var = 0.f;
#pragma unroll
  for (int q = 0; q < 8; ++q) { const float d = h[q] - mu; var += d * d; }
  var *= 0.125f;
  const float inv = 1.0f / sqrtf(var + EPSLN);
  float ang[8];
#pragma unroll
  for (int q = 0; q < 8; ++q)
    ang[q] = (h[q] - mu) * inv * gamma[q] + beta[q];

  // ---- product state after enc + layer-0: psi_i = RZ(w1i)RX(w0i)RZ(a)RX(a)|0> ----
  v2f f0[8], f1[8];
#pragma unroll
  for (int i = 0; i < 8; ++i) {
    float sa, ca;
    __sincosf(0.5f * ang[i], &sa, &ca);
    const float p0r = ca * ca, p0i = -ca * sa;
    const float p1r = sa * sa, p1i = -sa * ca;
    const float c0 = cs[2 * i],       s0 = cs[2 * i + 1];        // RX(w[0,i])
    const float cz = cs[2 * (9 + i)], sz = cs[2 * (9 + i) + 1];  // RZ(w[1,i])
    const float q0r = c0 * p0r + s0 * p1i, q0i = c0 * p0i - s0 * p1r;
    const float q1r = s0 * p0i + c0 * p1r, q1i = -s0 * p0r + c0 * p1i;
    f0[i].x = cz * q0r + sz * q0i;  f0[i].y = cz * q0i - sz * q0r;
    f1[i].x = cz * q1r - sz * q1i;  f1[i].y = cz * q1i + sz * q1r;
  }

  // local tensor (wires 0,1) and lane factor (wires 2..7); wire8 = |0>
  v2f t01[4];
  t01[0] = cmul(f0[0], f0[1]);
  t01[1] = cmul(f1[0], f0[1]);
  t01[2] = cmul(f0[0], f1[1]);
  t01[3] = cmul(f1[0], f1[1]);
  v2f L = bw2 ? f1[2] : f0[2];
  L = cmul(L, bw3 ? f1[3] : f0[3]);
  L = cmul(L, bw4 ? f1[4] : f0[4]);
  L = cmul(L, bw5 ? f1[5] : f0[5]);
  L = cmul(L, bw6 ? f1[6] : f0[6]);
  L = cmul(L, bw7 ? f1[7] : f0[7]);

  v2f a[8];
#pragma unroll
  for (int r = 0; r < 4; ++r) a[r] = cmul(t01[r], L);
#pragma unroll
  for (int r = 4; r < 8; ++r) { a[r].x = 0.f; a[r].y = 0.f; }

  // ---- layers 1..3 ----
#define G(l, i) cs[2 * ((l) * 9 + (i))], cs[2 * ((l) * 9 + (i)) + 1]
#define LAYER(l)                                                                 \
  cnot01(a);               ry_local<0>(a, G(l,0)); rz_local<0>(a, G(l,0));       \
  cnot12(a, bpx);          ry_local<1>(a, G(l,1)); rz_local<1>(a, G(l,1));       \
  cnot_ll<3>(a, bw2, bpx); ry_lane<2>(a, G(l,2), bw2, bpx); rz_lane<2>(a, G(l,2), bw2); \
  cnot_ll<4>(a, bw3, bpx); ry_lane<3>(a, G(l,3), bw3, bpx); rz_lane<3>(a, G(l,3), bw3); \
  cnot_ll<5>(a, bw4, bpx); ry_lane<4>(a, G(l,4), bw4, bpx); rz_lane<4>(a, G(l,4), bw4); \
  cnot_ll<6>(a, bw5, bpx); ry_lane<5>(a, G(l,5), bw5, bpx); rz_lane<5>(a, G(l,5), bw5); \
  cnot_ll<7>(a, bw6, bpx); ry_lane<6>(a, G(l,6), bw6, bpx); rz_lane<6>(a, G(l,6), bw6); \
  cnot_lt<0>(a, bw7);      ry_lane<7>(a, G(l,7), bw7, bpx); rz_lane<7>(a, G(l,7), bw7); \
  cnot_lt<2>(a, bw7);      ry_local<2>(a, G(l,8));
  LAYER(1) LAYER(2) LAYER(3)
#undef LAYER
#undef G

  // ---- measurement ----
  float p[8];
#pragma unroll
  for (int r = 0; r < 8; ++r) p[r] = fmaf(a[r].x, a[r].x, a[r].y * a[r].y);
  const float S = ((p[0] + p[1]) + (p[2] + p[3])) + ((p[4] + p[5]) + (p[6] + p[7]));
  float zz[2];
  zz[0] = ((p[0] - p[1]) + (p[2] - p[3])) + ((p[4] - p[5]) + (p[6] - p[7]));  // wire0
  zz[1] = ((p[0] + p[1]) - (p[2] + p[3])) + ((p[4] + p[5]) - (p[6] + p[7]));  // wire1
  allred(zz, bpx);

  // Walsh-Hadamard over lanes: after 6 butterflies, lane j holds
  // sum_l (-1)^{popcount(j&l)} S_l; z of lane-wire w = value at lane wmask(w).
  float sg[6];
#pragma unroll
  for (int b = 0; b < 6; ++b) sg[b] = ((lane >> b) & 1) ? -1.f : 1.f;
  float W = S, t_;
  t_ = lxor<1>(W, bpx);  W = fmaf(sg[0], W, t_);
  t_ = lxor<2>(W, bpx);  W = fmaf(sg[1], W, t_);
  t_ = lxor<4>(W, bpx);  W = fmaf(sg[2], W, t_);
  t_ = lxor<8>(W, bpx);  W = fmaf(sg[3], W, t_);
  t_ = lxor<16>(W, bpx); W = fmaf(sg[4], W, t_);
  t_ = lxor<32>(W, bpx); W = fmaf(sg[5], W, t_);

  float z[8];
  z[0] = rdfirst(zz[0]);
  z[1] = rdfirst(zz[1]);
  z[2] = rdlane(W, 4);    // wire2: mask 4
  z[3] = rdlane(W, 1);    // wire3: mask 1
  z[4] = rdlane(W, 2);    // wire4: mask 2
  z[5] = rdlane(W, 8);    // wire5: mask 8
  z[6] = rdlane(W, 16);   // wire6: mask 16
  z[7] = rdlane(W, 32);   // wire7: mask 32

  // ---- output projection + residual ----
  float* orow = out + (size_t)row * DIM;
  float4* ov = (float4*)orow;
  const float4* bv = (const float4*)b_out;
#pragma unroll
  for (int k = 0; k < 3; ++k) {
    const int j4 = lane + 64 * k;
    const float4 b4 = bv[j4];
    const float4* wo = (const float4*)(w_out + (size_t)j4 * 32);
    const float4 r0a = wo[0], r0b = wo[1];
    const float4 r1a = wo[2], r1b = wo[3];
    const float4 r2a = wo[4], r2b = wo[5];
    const float4 r3a = wo[6], r3b = wo[7];
    float4 o;
    o.x = xr[k].x + b4.x + z[0]*r0a.x + z[1]*r0a.y + z[2]*r0a.z + z[3]*r0a.w
                        + z[4]*r0b.x + z[5]*r0b.y + z[6]*r0b.z + z[7]*r0b.w;
    o.y = xr[k].y + b4.y + z[0]*r1a.x + z[1]*r1a.y + z[2]*r1a.z + z[3]*r1a.w
                        + z[4]*r1b.x + z[5]*r1b.y + z[6]*r1b.z + z[7]*r1b.w;
    o.z = xr[k].z + b4.z + z[0]*r2a.x + z[1]*r2a.y + z[2]*r2a.z + z[3]*r2a.w
                        + z[4]*r2b.x + z[5]*r2b.y + z[6]*r2b.z + z[7]*r2b.w;
    o.w = xr[k].w + b4.w + z[0]*r3a.x + z[1]*r3a.y + z[2]*r3a.z + z[3]*r3a.w
                        + z[4]*r3b.x + z[5]*r3b.y + z[6]*r3b.z + z[7]*r3b.w;
    ov[j4] = o;
  }
}

extern "C" void kernel_launch(void* const* d_in, const int* in_sizes, int n_in,
                              void* d_out, int out_size, void* d_ws, size_t ws_size,
                              hipStream_t stream) {
  const float* x     = (const float*)d_in[0];
  const float* w_in  = (const float*)d_in[1];
  const float* b_in  = (const float*)d_in[2];
  const float* gamma = (const float*)d_in[3];
  const float* beta  = (const float*)d_in[4];
  const float* q_w   = (const float*)d_in[5];
  const float* w_out = (const float*)d_in[6];
  const float* b_out = (const float*)d_in[7];
  float* outp = (float*)d_out;
  float* cs   = (float*)d_ws;   // 72 floats: (cos, sin) of q_w/2

  hipLaunchKernelGGL(precompute_trig, dim3(1), dim3(64), 0, stream, q_w, cs);
  hipLaunchKernelGGL(quantum_fused, dim3(BATCH / 4), dim3(256), 0, stream,
                     x, w_in, b_in, gamma, beta, w_out, b_out, cs, outp);
}